// Round 4
// baseline (167.464 us; speedup 1.0000x reference)
//
#include <hip/hip_runtime.h>

#define NT 256          // f(x) table size
#define NBATCH 1024
#define NOUT 65536      // 1024*64

#if __has_builtin(__builtin_amdgcn_exp2f)
#define EXP2(x) __builtin_amdgcn_exp2f(x)
#else
#define EXP2(x) exp2f(x)
#endif

// ---- graph constants (baked from the reference) ----
__constant__ int c_e1[17] = {0,0,1,2,2,3,4,5,6,8,8,9,10,11,11,13,14};
__constant__ int c_e2[17] = {1,4,2,3,5,4,12,6,7,9,12,10,11,12,13,14,15};
__constant__ int c_p0[24] = {1,0,1,1,3,2,0,0,3,2,5,5,9,8,9,10,10,12,4,4,8,11,13,13};
__constant__ int c_p1[24] = {4,2,3,5,5,4,3,12,12,6,7,6,12,10,11,11,13,13,8,11,11,14,15,14};
__constant__ int c_ni[24] = {0,1,2,2,2,3,4,4,4,5,6,7,8,9,10,11,11,11,12,12,12,13,14,15};

// 9 ordered products (left a, right b): grouped by right side js (group g),
// slot u in group => left block = u, scale combo = c_gc[g*3+u]
__constant__ int c_gc[9] = {0,1,2, 1,3,4, 2,4,5};
__constant__ int c_ca[6] = {0,0,0,1,1,2};
__constant__ int c_cb[6] = {0,1,2,1,2,2};

// monotonic float<->uint encoding for atomicMin/Max on floats
__device__ __forceinline__ unsigned encf(float f) {
  unsigned u = __float_as_uint(f);
  return (u & 0x80000000u) ? ~u : (u | 0x80000000u);
}
__device__ __forceinline__ float decf(unsigned e) {
  unsigned u = (e & 0x80000000u) ? (e & 0x7FFFFFFFu) : ~e;
  return __uint_as_float(u);
}

// ---- kernel 1: per-batch ovl (8x8) = sum over 9 ordered products, fused ----
__global__ __launch_bounds__(256, 4)
void k_ovl(const float* __restrict__ pos, const float* __restrict__ cg,
           const float* __restrict__ sigp, float* __restrict__ xout,
           unsigned* __restrict__ mm) {
  __shared__ float posS[48];
  __shared__ __align__(16) float P4[81][4];       // xyz + r2 in w
  __shared__ __align__(16) float CT[3][81][8];    // C' per block: CT[blk][j][q]
  __shared__ float ovl64[64][65];                 // 64 padded accumulation copies
  __shared__ float gInv[9], gLgp[9];              // per (group,slot): nInv*log2e, log2(pref)
  __shared__ float red[4][64];

  const int b = blockIdx.x;
  const int t = threadIdx.x;

  if (t < 48) posS[t] = pos[b * 48 + t];

  // make_opposite_blocks forward: odd cross cols (bp>=33, odd offset) = -C[:,col-1]
  for (int idx = t; idx < 3 * 81 * 8; idx += 256) {
    int s = idx / 648;
    int rem = idx - s * 648;
    int j = rem >> 3, q = rem & 7;
    int col = s * 81 + j;
    int off = j - 33;
    float v;
    if (off >= 0 && (off & 1)) v = -cg[q * 243 + (col - 1)];
    else                       v =  cg[q * 243 + col];
    CT[s][j][q] = v;
  }

  // zero the 64 accumulation copies (+ padding)
  for (int idx = t; idx < 64 * 65; idx += 256) ((float*)ovl64)[idx] = 0.0f;

  if (t == 0) {
    float sg[3];
    sg[0] = 0.4f * __expf(sigp[0]);
    sg[1] = 0.8f * __expf(sigp[1]);
    sg[2] = 1.2f * __expf(sigp[2]);
    float nI[6], lg[6];
    #pragma unroll
    for (int c = 0; c < 6; ++c) {
      float sa = sg[c_ca[c]], sb = sg[c_cb[c]];
      float s2 = sa * sa + sb * sb;
      float rr = 2.0f * sa * sb / s2;
      lg[c] = 1.5f * __log2f(rr);                 // log2(pref) folded into exp arg
      nI[c] = (-0.5f / s2) * 1.44269504088896f;   // includes log2(e)
    }
    #pragma unroll
    for (int gi = 0; gi < 9; ++gi) { gInv[gi] = nI[c_gc[gi]]; gLgp[gi] = lg[c_gc[gi]]; }
  }
  __syncthreads();

  // 81 block points: 16 atoms, 17 bond midpoints, 24 pairs x 2 cross points
  if (t < 81) {
    float x, y, z;
    if (t < 16) {
      x = posS[t * 3]; y = posS[t * 3 + 1]; z = posS[t * 3 + 2];
    } else if (t < 33) {
      int e = t - 16;
      int a0 = c_e1[e] * 3, a1 = c_e2[e] * 3;
      x = 0.5f * (posS[a0] + posS[a1]);
      y = 0.5f * (posS[a0 + 1] + posS[a1 + 1]);
      z = 0.5f * (posS[a0 + 2] + posS[a1 + 2]);
    } else {
      int k = (t - 33) >> 1, sgn = (t - 33) & 1;
      float sc = sgn ? 0.25f : -0.25f;
      int n = c_ni[k] * 3, a0 = c_p0[k] * 3, a1 = c_p1[k] * 3;
      x = posS[n]     + sc * (posS[a0]     - posS[a1]);
      y = posS[n + 1] + sc * (posS[a0 + 1] - posS[a1 + 1]);
      z = posS[n + 2] + sc * (posS[a0 + 2] - posS[a1 + 2]);
    }
    P4[t][0] = x; P4[t][1] = y; P4[t][2] = z;
    P4[t][3] = x * x + y * y + z * z;
  }
  __syncthreads();

  // ---- fused V + outer product: 243 tasks = (group g, 3-row strip r, 27-j chunk k)
  if (t < 243) {
    const int g = t / 81;
    const int rem = t - g * 81;
    const int r = rem / 3;
    const int k = rem - r * 3;
    const int i0 = r * 3;
    const int jbase = k * 27;
    const int lane64 = t & 63;

    float nInv[3], lgp[3];
    #pragma unroll
    for (int u = 0; u < 3; ++u) { nInv[u] = gInv[g * 3 + u]; lgp[u] = gLgp[g * 3 + u]; }

    const float4 pA = *(const float4*)P4[i0];
    const float4 pB = *(const float4*)P4[i0 + 1];
    const float4 pC = *(const float4*)P4[i0 + 2];

    float vacc[3][3][8];
    #pragma unroll
    for (int u = 0; u < 3; ++u)
      #pragma unroll
      for (int rw = 0; rw < 3; ++rw)
        #pragma unroll
        for (int q = 0; q < 8; ++q) vacc[u][rw][q] = 0.0f;

    #pragma unroll 3
    for (int jj = 0; jj < 27; ++jj) {
      const int j = jbase + jj;
      const float4 pj = *(const float4*)P4[j];
      const float dA = pA.x * pj.x + pA.y * pj.y + pA.z * pj.z;
      const float dB = pB.x * pj.x + pB.y * pj.y + pB.z * pj.z;
      const float dC = pC.x * pj.x + pC.y * pj.y + pC.z * pj.z;
      const float d2A = fmaf(-2.0f, dA, pA.w + pj.w);
      const float d2B = fmaf(-2.0f, dB, pB.w + pj.w);
      const float d2C = fmaf(-2.0f, dC, pC.w + pj.w);
      const float4 cb0 = *(const float4*)&CT[g][j][0];
      const float4 cb1 = *(const float4*)&CT[g][j][4];
      #pragma unroll
      for (int u = 0; u < 3; ++u) {
        const float eA = EXP2(fmaf(nInv[u], d2A, lgp[u]));
        const float eB = EXP2(fmaf(nInv[u], d2B, lgp[u]));
        const float eC = EXP2(fmaf(nInv[u], d2C, lgp[u]));
        vacc[u][0][0] += eA * cb0.x; vacc[u][0][1] += eA * cb0.y;
        vacc[u][0][2] += eA * cb0.z; vacc[u][0][3] += eA * cb0.w;
        vacc[u][0][4] += eA * cb1.x; vacc[u][0][5] += eA * cb1.y;
        vacc[u][0][6] += eA * cb1.z; vacc[u][0][7] += eA * cb1.w;
        vacc[u][1][0] += eB * cb0.x; vacc[u][1][1] += eB * cb0.y;
        vacc[u][1][2] += eB * cb0.z; vacc[u][1][3] += eB * cb0.w;
        vacc[u][1][4] += eB * cb1.x; vacc[u][1][5] += eB * cb1.y;
        vacc[u][1][6] += eB * cb1.z; vacc[u][1][7] += eB * cb1.w;
        vacc[u][2][0] += eC * cb0.x; vacc[u][2][1] += eC * cb0.y;
        vacc[u][2][2] += eC * cb0.z; vacc[u][2][3] += eC * cb0.w;
        vacc[u][2][4] += eC * cb1.x; vacc[u][2][5] += eC * cb1.y;
        vacc[u][2][6] += eC * cb1.z; vacc[u][2][7] += eC * cb1.w;
      }
    }

    // outer product: ovl[p][q] += CT_left=u[i0+rw][p] * vacc[u][rw][q]
    // (pref already folded into vacc via exp arg)
    #pragma unroll
    for (int pg = 0; pg < 8; pg += 4) {
      float4 ctv[3][3];
      #pragma unroll
      for (int u = 0; u < 3; ++u)
        #pragma unroll
        for (int rw = 0; rw < 3; ++rw)
          ctv[u][rw] = *(const float4*)&CT[u][i0 + rw][pg];
      #pragma unroll
      for (int po = 0; po < 4; ++po) {
        const int p = pg + po;
        float o[8];
        #pragma unroll
        for (int q = 0; q < 8; ++q) o[q] = 0.0f;
        #pragma unroll
        for (int u = 0; u < 3; ++u) {
          #pragma unroll
          for (int rw = 0; rw < 3; ++rw) {
            const float ct = po == 0 ? ctv[u][rw].x : po == 1 ? ctv[u][rw].y
                           : po == 2 ? ctv[u][rw].z : ctv[u][rw].w;
            #pragma unroll
            for (int q = 0; q < 8; ++q) o[q] += ct * vacc[u][rw][q];
          }
        }
        #pragma unroll
        for (int q = 0; q < 8; ++q)
          atomicAdd(&ovl64[lane64][p * 8 + q], o[q]);
      }
    }
  }
  __syncthreads();

  // ---- reduce the 64 copies ----
  {
    const int w = t >> 6;
    const int m = t & 63;
    float part = 0.0f;
    #pragma unroll
    for (int it = 0; it < 16; ++it) part += ovl64[w * 16 + it][m];
    red[w][m] = part;
  }
  __syncthreads();

  if (t < 64) {
    const float v = red[0][t] + red[1][t] + red[2][t] + red[3][t];
    xout[b * 64 + t] = v;
    float vmin = v, vmax = v;
    #pragma unroll
    for (int off = 32; off; off >>= 1) {
      vmin = fminf(vmin, __shfl_down(vmin, off));
      vmax = fmaxf(vmax, __shfl_down(vmax, off));
    }
    if (t == 0) {
      atomicMin(&mm[0], encf(vmin));
      atomicMax(&mm[1], encf(vmax));
    }
  }
}

// ---- kernel 2: tabulate f(x) at NT nodes; full fp32 MLP per node ----
__device__ __forceinline__ float dot128(const float* __restrict__ W,
                                        const float* __restrict__ act, int t) {
  const float4* w4 = (const float4*)(W + (size_t)t * 128);
  const float4* a4 = (const float4*)act;
  float acc = 0.0f;
  #pragma unroll
  for (int kq = 0; kq < 32; ++kq) {
    float4 w = w4[kq];
    float4 a = a4[kq];
    acc += w.x * a.x + w.y * a.y + w.z * a.z + w.w * a.w;
  }
  return acc;
}

__global__ __launch_bounds__(128)
void k_table(const float* __restrict__ ew, const float* __restrict__ eb,
             const float* __restrict__ mup, const float* __restrict__ lrp,
             const float* __restrict__ W1, const float* __restrict__ b1,
             const float* __restrict__ W2, const float* __restrict__ b2,
             const float* __restrict__ W3, const float* __restrict__ b3,
             const unsigned* __restrict__ mm, float* __restrict__ table) {
  __shared__ __align__(16) float actA[128];
  __shared__ __align__(16) float actB[128];
  __shared__ float red[2];
  __shared__ float red2[2];
  const int t = threadIdx.x;
  const int wv = t >> 6;

  const float xmin = decf(mm[0]);
  const float xmax = decf(mm[1]);
  const float x = xmin + (xmax - xmin) * ((float)blockIdx.x / (float)(NT - 1));

  // encoder softmax: e = softmax(ew*x + eb)
  float lg = ew[t] * x + eb[t];
  float m = lg;
  #pragma unroll
  for (int off = 32; off; off >>= 1) m = fmaxf(m, __shfl_xor(m, off));
  if ((t & 63) == 0) red[wv] = m;
  __syncthreads();
  m = fmaxf(red[0], red[1]);
  float ev = __expf(lg - m);
  float s = ev;
  #pragma unroll
  for (int off = 32; off; off >>= 1) s += __shfl_xor(s, off);
  if ((t & 63) == 0) red2[wv] = s;
  __syncthreads();
  s = red2[0] + red2[1];
  actA[t] = ev / s;
  __syncthreads();

  float h = fmaxf(b1[t] + dot128(W1, actA, t), 0.0f);
  actB[t] = h;
  __syncthreads();
  h = fmaxf(b2[t] + dot128(W2, actB, t), 0.0f);
  actA[t] = h;
  __syncthreads();
  float h3 = b3[t] + dot128(W3, actA, t);

  float m3 = h3;
  #pragma unroll
  for (int off = 32; off; off >>= 1) m3 = fmaxf(m3, __shfl_xor(m3, off));
  __syncthreads();
  if ((t & 63) == 0) red[wv] = m3;
  __syncthreads();
  m3 = fmaxf(red[0], red[1]);
  float e3 = __expf(h3 - m3);
  float dn = e3;
  float nm = e3 * mup[t];
  #pragma unroll
  for (int off = 32; off; off >>= 1) {
    dn += __shfl_xor(dn, off);
    nm += __shfl_xor(nm, off);
  }
  __syncthreads();
  if ((t & 63) == 0) { red[wv] = dn; red2[wv] = nm; }
  __syncthreads();
  if (t == 0)
    table[blockIdx.x] = lrp[0] * ((red2[0] + red2[1]) / (red[0] + red[1]));
}

// ---- kernel 3: linear interpolation of the table at each x ----
__global__ __launch_bounds__(256)
void k_interp(const float* __restrict__ xbuf, const float* __restrict__ table,
              const unsigned* __restrict__ mm, float* __restrict__ out, int n) {
  const int r = blockIdx.x * 256 + threadIdx.x;
  if (r >= n) return;
  const float xmin = decf(mm[0]);
  const float xmax = decf(mm[1]);
  const float range = xmax - xmin;
  const float scale = (range > 0.0f) ? (float)(NT - 1) / range : 0.0f;
  float p = (xbuf[r] - xmin) * scale;
  int i0 = (int)floorf(p);
  i0 = min(max(i0, 0), NT - 2);
  const float w = p - (float)i0;
  out[r] = table[i0] + w * (table[i0 + 1] - table[i0]);
}

extern "C" void kernel_launch(void* const* d_in, const int* in_sizes, int n_in,
                              void* d_out, int out_size, void* d_ws, size_t ws_size,
                              hipStream_t stream) {
  const float* pos  = (const float*)d_in[0];
  const float* cg   = (const float*)d_in[1];
  const float* sigp = (const float*)d_in[2];
  const float* ew   = (const float*)d_in[3];
  const float* eb   = (const float*)d_in[4];
  const float* mup  = (const float*)d_in[5];
  const float* lrp  = (const float*)d_in[6];
  const float* W1   = (const float*)d_in[7];
  const float* b1   = (const float*)d_in[8];
  const float* W2   = (const float*)d_in[9];
  const float* b2   = (const float*)d_in[10];
  const float* W3   = (const float*)d_in[11];
  const float* b3   = (const float*)d_in[12];
  float* out = (float*)d_out;

  unsigned* mm = (unsigned*)d_ws;
  float* xbuf  = (float*)d_ws + 16;
  float* table = xbuf + NOUT;

  hipMemsetAsync(mm, 0xFF, 4, stream);      // encoded running min = 0xFFFFFFFF
  hipMemsetAsync(mm + 1, 0x00, 4, stream);  // encoded running max = 0
  k_ovl<<<NBATCH, 256, 0, stream>>>(pos, cg, sigp, xbuf, mm);
  k_table<<<NT, 128, 0, stream>>>(ew, eb, mup, lrp, W1, b1, W2, b2, W3, b3, mm, table);
  k_interp<<<(NOUT + 255) / 256, 256, 0, stream>>>(xbuf, table, mm, out, NOUT);
}

// Round 5
// 129.895 us; speedup vs baseline: 1.2892x; 1.2892x over previous
//
#include <hip/hip_runtime.h>

#define NT 256          // f(x) table size
#define NBATCH 1024
#define NOUT 65536      // 1024*64

#if __has_builtin(__builtin_amdgcn_exp2f)
#define EXP2(x) __builtin_amdgcn_exp2f(x)
#else
#define EXP2(x) exp2f(x)
#endif

// ---- graph constants (baked from the reference) ----
__constant__ int c_e1[17] = {0,0,1,2,2,3,4,5,6,8,8,9,10,11,11,13,14};
__constant__ int c_e2[17] = {1,4,2,3,5,4,12,6,7,9,12,10,11,12,13,14,15};
__constant__ int c_p0[24] = {1,0,1,1,3,2,0,0,3,2,5,5,9,8,9,10,10,12,4,4,8,11,13,13};
__constant__ int c_p1[24] = {4,2,3,5,5,4,3,12,12,6,7,6,12,10,11,11,13,13,8,11,11,14,15,14};
__constant__ int c_ni[24] = {0,1,2,2,2,3,4,4,4,5,6,7,8,9,10,11,11,11,12,12,12,13,14,15};

// 9 ordered products (left a, right b): grouped by right side js (group g),
// slot u in group => left block = u, scale combo = c_gc[g*3+u]
__constant__ int c_gc[9] = {0,1,2, 1,3,4, 2,4,5};
__constant__ int c_ca[6] = {0,0,0,1,1,2};
__constant__ int c_cb[6] = {0,1,2,1,2,2};

// monotonic float<->uint encoding for atomicMin/Max on floats
__device__ __forceinline__ unsigned encf(float f) {
  unsigned u = __float_as_uint(f);
  return (u & 0x80000000u) ? ~u : (u | 0x80000000u);
}
__device__ __forceinline__ float decf(unsigned e) {
  unsigned u = (e & 0x80000000u) ? (e & 0x7FFFFFFFu) : ~e;
  return __uint_as_float(u);
}

// ---- kernel 1: per-batch ovl (8x8) = sum over 9 ordered products, fused ----
// launch_bounds(256, 2): 256-VGPR budget — the 72-float vacc MUST stay in
// registers (with (256,4)'s 128-VGPR cap the compiler spilled to scratch:
// 193 MB/dispatch of HBM write traffic, 3.5x regression).
__global__ __launch_bounds__(256, 2)
void k_ovl(const float* __restrict__ pos, const float* __restrict__ cg,
           const float* __restrict__ sigp, float* __restrict__ xout,
           unsigned* __restrict__ mm) {
  __shared__ float posS[48];
  __shared__ __align__(16) float P4[81][4];       // xyz + r2 in w
  __shared__ __align__(16) float CT[3][81][8];    // C' per block: CT[blk][j][q]
  __shared__ float ovl64[64][65];                 // 64 padded accumulation copies
  __shared__ float gInv[9], gLgp[9];              // per (group,slot): nInv*log2e, log2(pref)
  __shared__ float red[4][64];

  const int b = blockIdx.x;
  const int t = threadIdx.x;

  if (t < 48) posS[t] = pos[b * 48 + t];

  // make_opposite_blocks forward: odd cross cols (bp>=33, odd offset) = -C[:,col-1]
  for (int idx = t; idx < 3 * 81 * 8; idx += 256) {
    int s = idx / 648;
    int rem = idx - s * 648;
    int j = rem >> 3, q = rem & 7;
    int col = s * 81 + j;
    int off = j - 33;
    float v;
    if (off >= 0 && (off & 1)) v = -cg[q * 243 + (col - 1)];
    else                       v =  cg[q * 243 + col];
    CT[s][j][q] = v;
  }

  // zero the 64 accumulation copies (+ padding)
  for (int idx = t; idx < 64 * 65; idx += 256) ((float*)ovl64)[idx] = 0.0f;

  if (t == 0) {
    float sg[3];
    sg[0] = 0.4f * __expf(sigp[0]);
    sg[1] = 0.8f * __expf(sigp[1]);
    sg[2] = 1.2f * __expf(sigp[2]);
    float nI[6], lg[6];
    #pragma unroll
    for (int c = 0; c < 6; ++c) {
      float sa = sg[c_ca[c]], sb = sg[c_cb[c]];
      float s2 = sa * sa + sb * sb;
      float rr = 2.0f * sa * sb / s2;
      lg[c] = 1.5f * __log2f(rr);                 // log2(pref) folded into exp arg
      nI[c] = (-0.5f / s2) * 1.44269504088896f;   // includes log2(e)
    }
    #pragma unroll
    for (int gi = 0; gi < 9; ++gi) { gInv[gi] = nI[c_gc[gi]]; gLgp[gi] = lg[c_gc[gi]]; }
  }
  __syncthreads();

  // 81 block points: 16 atoms, 17 bond midpoints, 24 pairs x 2 cross points
  if (t < 81) {
    float x, y, z;
    if (t < 16) {
      x = posS[t * 3]; y = posS[t * 3 + 1]; z = posS[t * 3 + 2];
    } else if (t < 33) {
      int e = t - 16;
      int a0 = c_e1[e] * 3, a1 = c_e2[e] * 3;
      x = 0.5f * (posS[a0] + posS[a1]);
      y = 0.5f * (posS[a0 + 1] + posS[a1 + 1]);
      z = 0.5f * (posS[a0 + 2] + posS[a1 + 2]);
    } else {
      int k = (t - 33) >> 1, sgn = (t - 33) & 1;
      float sc = sgn ? 0.25f : -0.25f;
      int n = c_ni[k] * 3, a0 = c_p0[k] * 3, a1 = c_p1[k] * 3;
      x = posS[n]     + sc * (posS[a0]     - posS[a1]);
      y = posS[n + 1] + sc * (posS[a0 + 1] - posS[a1 + 1]);
      z = posS[n + 2] + sc * (posS[a0 + 2] - posS[a1 + 2]);
    }
    P4[t][0] = x; P4[t][1] = y; P4[t][2] = z;
    P4[t][3] = x * x + y * y + z * z;
  }
  __syncthreads();

  // ---- fused V + outer product: 243 tasks = (group g, 3-row strip r, 27-j chunk k)
  if (t < 243) {
    const int g = t / 81;
    const int rem = t - g * 81;
    const int r = rem / 3;
    const int k = rem - r * 3;
    const int i0 = r * 3;
    const int jbase = k * 27;
    const int lane64 = t & 63;

    float nInv[3], lgp[3];
    #pragma unroll
    for (int u = 0; u < 3; ++u) { nInv[u] = gInv[g * 3 + u]; lgp[u] = gLgp[g * 3 + u]; }

    const float4 pA = *(const float4*)P4[i0];
    const float4 pB = *(const float4*)P4[i0 + 1];
    const float4 pC = *(const float4*)P4[i0 + 2];

    float vacc[3][3][8];
    #pragma unroll
    for (int u = 0; u < 3; ++u)
      #pragma unroll
      for (int rw = 0; rw < 3; ++rw)
        #pragma unroll
        for (int q = 0; q < 8; ++q) vacc[u][rw][q] = 0.0f;

    #pragma unroll 3
    for (int jj = 0; jj < 27; ++jj) {
      const int j = jbase + jj;
      const float4 pj = *(const float4*)P4[j];
      const float dA = pA.x * pj.x + pA.y * pj.y + pA.z * pj.z;
      const float dB = pB.x * pj.x + pB.y * pj.y + pB.z * pj.z;
      const float dC = pC.x * pj.x + pC.y * pj.y + pC.z * pj.z;
      const float d2A = fmaf(-2.0f, dA, pA.w + pj.w);
      const float d2B = fmaf(-2.0f, dB, pB.w + pj.w);
      const float d2C = fmaf(-2.0f, dC, pC.w + pj.w);
      const float4 cb0 = *(const float4*)&CT[g][j][0];
      const float4 cb1 = *(const float4*)&CT[g][j][4];
      #pragma unroll
      for (int u = 0; u < 3; ++u) {
        const float eA = EXP2(fmaf(nInv[u], d2A, lgp[u]));
        const float eB = EXP2(fmaf(nInv[u], d2B, lgp[u]));
        const float eC = EXP2(fmaf(nInv[u], d2C, lgp[u]));
        vacc[u][0][0] += eA * cb0.x; vacc[u][0][1] += eA * cb0.y;
        vacc[u][0][2] += eA * cb0.z; vacc[u][0][3] += eA * cb0.w;
        vacc[u][0][4] += eA * cb1.x; vacc[u][0][5] += eA * cb1.y;
        vacc[u][0][6] += eA * cb1.z; vacc[u][0][7] += eA * cb1.w;
        vacc[u][1][0] += eB * cb0.x; vacc[u][1][1] += eB * cb0.y;
        vacc[u][1][2] += eB * cb0.z; vacc[u][1][3] += eB * cb0.w;
        vacc[u][1][4] += eB * cb1.x; vacc[u][1][5] += eB * cb1.y;
        vacc[u][1][6] += eB * cb1.z; vacc[u][1][7] += eB * cb1.w;
        vacc[u][2][0] += eC * cb0.x; vacc[u][2][1] += eC * cb0.y;
        vacc[u][2][2] += eC * cb0.z; vacc[u][2][3] += eC * cb0.w;
        vacc[u][2][4] += eC * cb1.x; vacc[u][2][5] += eC * cb1.y;
        vacc[u][2][6] += eC * cb1.z; vacc[u][2][7] += eC * cb1.w;
      }
    }

    // outer product: ovl[p][q] += CT_left=u[i0+rw][p] * vacc[u][rw][q]
    // (pref already folded into vacc via exp arg)
    #pragma unroll
    for (int pg = 0; pg < 8; pg += 4) {
      float4 ctv[3][3];
      #pragma unroll
      for (int u = 0; u < 3; ++u)
        #pragma unroll
        for (int rw = 0; rw < 3; ++rw)
          ctv[u][rw] = *(const float4*)&CT[u][i0 + rw][pg];
      #pragma unroll
      for (int po = 0; po < 4; ++po) {
        const int p = pg + po;
        float o[8];
        #pragma unroll
        for (int q = 0; q < 8; ++q) o[q] = 0.0f;
        #pragma unroll
        for (int u = 0; u < 3; ++u) {
          #pragma unroll
          for (int rw = 0; rw < 3; ++rw) {
            const float ct = po == 0 ? ctv[u][rw].x : po == 1 ? ctv[u][rw].y
                           : po == 2 ? ctv[u][rw].z : ctv[u][rw].w;
            #pragma unroll
            for (int q = 0; q < 8; ++q) o[q] += ct * vacc[u][rw][q];
          }
        }
        #pragma unroll
        for (int q = 0; q < 8; ++q)
          atomicAdd(&ovl64[lane64][p * 8 + q], o[q]);
      }
    }
  }
  __syncthreads();

  // ---- reduce the 64 copies ----
  {
    const int w = t >> 6;
    const int m = t & 63;
    float part = 0.0f;
    #pragma unroll
    for (int it = 0; it < 16; ++it) part += ovl64[w * 16 + it][m];
    red[w][m] = part;
  }
  __syncthreads();

  if (t < 64) {
    const float v = red[0][t] + red[1][t] + red[2][t] + red[3][t];
    xout[b * 64 + t] = v;
    float vmin = v, vmax = v;
    #pragma unroll
    for (int off = 32; off; off >>= 1) {
      vmin = fminf(vmin, __shfl_down(vmin, off));
      vmax = fmaxf(vmax, __shfl_down(vmax, off));
    }
    if (t == 0) {
      atomicMin(&mm[0], encf(vmin));
      atomicMax(&mm[1], encf(vmax));
    }
  }
}

// ---- kernel 2: tabulate f(x) at NT nodes; full fp32 MLP per node ----
__device__ __forceinline__ float dot128(const float* __restrict__ W,
                                        const float* __restrict__ act, int t) {
  const float4* w4 = (const float4*)(W + (size_t)t * 128);
  const float4* a4 = (const float4*)act;
  float acc = 0.0f;
  #pragma unroll
  for (int kq = 0; kq < 32; ++kq) {
    float4 w = w4[kq];
    float4 a = a4[kq];
    acc += w.x * a.x + w.y * a.y + w.z * a.z + w.w * a.w;
  }
  return acc;
}

__global__ __launch_bounds__(128)
void k_table(const float* __restrict__ ew, const float* __restrict__ eb,
             const float* __restrict__ mup, const float* __restrict__ lrp,
             const float* __restrict__ W1, const float* __restrict__ b1,
             const float* __restrict__ W2, const float* __restrict__ b2,
             const float* __restrict__ W3, const float* __restrict__ b3,
             const unsigned* __restrict__ mm, float* __restrict__ table) {
  __shared__ __align__(16) float actA[128];
  __shared__ __align__(16) float actB[128];
  __shared__ float red[2];
  __shared__ float red2[2];
  const int t = threadIdx.x;
  const int wv = t >> 6;

  const float xmin = decf(mm[0]);
  const float xmax = decf(mm[1]);
  const float x = xmin + (xmax - xmin) * ((float)blockIdx.x / (float)(NT - 1));

  // encoder softmax: e = softmax(ew*x + eb)
  float lg = ew[t] * x + eb[t];
  float m = lg;
  #pragma unroll
  for (int off = 32; off; off >>= 1) m = fmaxf(m, __shfl_xor(m, off));
  if ((t & 63) == 0) red[wv] = m;
  __syncthreads();
  m = fmaxf(red[0], red[1]);
  float ev = __expf(lg - m);
  float s = ev;
  #pragma unroll
  for (int off = 32; off; off >>= 1) s += __shfl_xor(s, off);
  if ((t & 63) == 0) red2[wv] = s;
  __syncthreads();
  s = red2[0] + red2[1];
  actA[t] = ev / s;
  __syncthreads();

  float h = fmaxf(b1[t] + dot128(W1, actA, t), 0.0f);
  actB[t] = h;
  __syncthreads();
  h = fmaxf(b2[t] + dot128(W2, actB, t), 0.0f);
  actA[t] = h;
  __syncthreads();
  float h3 = b3[t] + dot128(W3, actA, t);

  float m3 = h3;
  #pragma unroll
  for (int off = 32; off; off >>= 1) m3 = fmaxf(m3, __shfl_xor(m3, off));
  __syncthreads();
  if ((t & 63) == 0) red[wv] = m3;
  __syncthreads();
  m3 = fmaxf(red[0], red[1]);
  float e3 = __expf(h3 - m3);
  float dn = e3;
  float nm = e3 * mup[t];
  #pragma unroll
  for (int off = 32; off; off >>= 1) {
    dn += __shfl_xor(dn, off);
    nm += __shfl_xor(nm, off);
  }
  __syncthreads();
  if ((t & 63) == 0) { red[wv] = dn; red2[wv] = nm; }
  __syncthreads();
  if (t == 0)
    table[blockIdx.x] = lrp[0] * ((red2[0] + red2[1]) / (red[0] + red[1]));
}

// ---- kernel 3: linear interpolation of the table at each x ----
__global__ __launch_bounds__(256)
void k_interp(const float* __restrict__ xbuf, const float* __restrict__ table,
              const unsigned* __restrict__ mm, float* __restrict__ out, int n) {
  const int r = blockIdx.x * 256 + threadIdx.x;
  if (r >= n) return;
  const float xmin = decf(mm[0]);
  const float xmax = decf(mm[1]);
  const float range = xmax - xmin;
  const float scale = (range > 0.0f) ? (float)(NT - 1) / range : 0.0f;
  float p = (xbuf[r] - xmin) * scale;
  int i0 = (int)floorf(p);
  i0 = min(max(i0, 0), NT - 2);
  const float w = p - (float)i0;
  out[r] = table[i0] + w * (table[i0 + 1] - table[i0]);
}

extern "C" void kernel_launch(void* const* d_in, const int* in_sizes, int n_in,
                              void* d_out, int out_size, void* d_ws, size_t ws_size,
                              hipStream_t stream) {
  const float* pos  = (const float*)d_in[0];
  const float* cg   = (const float*)d_in[1];
  const float* sigp = (const float*)d_in[2];
  const float* ew   = (const float*)d_in[3];
  const float* eb   = (const float*)d_in[4];
  const float* mup  = (const float*)d_in[5];
  const float* lrp  = (const float*)d_in[6];
  const float* W1   = (const float*)d_in[7];
  const float* b1   = (const float*)d_in[8];
  const float* W2   = (const float*)d_in[9];
  const float* b2   = (const float*)d_in[10];
  const float* W3   = (const float*)d_in[11];
  const float* b3   = (const float*)d_in[12];
  float* out = (float*)d_out;

  unsigned* mm = (unsigned*)d_ws;
  float* xbuf  = (float*)d_ws + 16;
  float* table = xbuf + NOUT;

  hipMemsetAsync(mm, 0xFF, 4, stream);      // encoded running min = 0xFFFFFFFF
  hipMemsetAsync(mm + 1, 0x00, 4, stream);  // encoded running max = 0
  k_ovl<<<NBATCH, 256, 0, stream>>>(pos, cg, sigp, xbuf, mm);
  k_table<<<NT, 128, 0, stream>>>(ew, eb, mup, lrp, W1, b1, W2, b2, W3, b3, mm, table);
  k_interp<<<(NOUT + 255) / 256, 256, 0, stream>>>(xbuf, table, mm, out, NOUT);
}